// Round 1
// baseline (687.322 us; speedup 1.0000x reference)
//
#include <hip/hip_runtime.h>
#include <math.h>

#define HIDDEN 128

// One block (256 threads) per graph.
// Phase 1: binary-search segment bounds in sorted `batch`.
// Phase 2: coalesced float4 streaming reduce (sum + max) over the segment rows.
// Phase 3: pooled[384] = [mean | max | sum] in LDS.
// Phase 4: h = pooled @ W + b (k split over 2 halves of the block, W from L2).
// Phase 5: LayerNorm (eps=1e-5) + exact GELU, write 128 floats.
__global__ __launch_bounds__(256) void mp_fused(
    const float* __restrict__ x,
    const void* __restrict__ batch_raw,
    const int n_nodes,
    const float* __restrict__ W,
    const float* __restrict__ bias,
    const float* __restrict__ gamma,
    const float* __restrict__ beta,
    float* __restrict__ out)
{
    const int g = blockIdx.x;
    const int t = threadIdx.x;

    __shared__ int bounds[2];
    __shared__ float4 lsum[8][32];
    __shared__ float4 lmax[8][32];
    __shared__ float pooled[3 * HIDDEN];
    __shared__ float hpart[2][HIDDEN];
    __shared__ float red[2];
    __shared__ float red2[2];

    // ---- Phase 1: segment bounds via binary search (lower_bound of g, g+1) ----
    if (t < 2) {
        const int* b32 = (const int*)batch_raw;
        // Robust int32-vs-int64 detection: batch is sorted, last graph id ~4095.
        // If stored as int64, word [n-1] is the HIGH word of a small value -> 0.
        const bool is64 = (b32[n_nodes - 1] == 0);
        const long long key = (long long)(g + t);
        int lo = 0, hi = n_nodes;
        while (lo < hi) {
            const int mid = (lo + hi) >> 1;
            const long long bv = is64 ? ((const long long*)batch_raw)[mid]
                                      : (long long)b32[mid];
            if (bv < key) lo = mid + 1; else hi = mid;
        }
        bounds[t] = lo;
    }
    __syncthreads();
    const int s   = bounds[0];
    const int cnt = bounds[1] - s;

    // ---- Phase 2: streaming reduce. lane layout: 32 col-groups x 8 row slots ----
    const int tcol = t & 31;   // 4-float column group
    const int slot = t >> 5;   // row slot 0..7
    float sx = 0.f, sy = 0.f, sz = 0.f, sw = 0.f;
    float mxx = -INFINITY, mxy = -INFINITY, mxz = -INFINITY, mxw = -INFINITY;
    const float* xp = x + (size_t)s * HIDDEN + (tcol << 2);
    for (int r = slot; r < cnt; r += 8) {
        const float4 v = *(const float4*)(xp + (size_t)r * HIDDEN);
        sx += v.x; sy += v.y; sz += v.z; sw += v.w;
        mxx = fmaxf(mxx, v.x); mxy = fmaxf(mxy, v.y);
        mxz = fmaxf(mxz, v.z); mxw = fmaxf(mxw, v.w);
    }
    lsum[slot][tcol] = make_float4(sx, sy, sz, sw);
    lmax[slot][tcol] = make_float4(mxx, mxy, mxz, mxw);
    __syncthreads();

    // ---- Phase 3: combine 8 slots, build pooled = [mean | max | sum] ----
    if (t < 32) {
        float4 ts = lsum[0][t];
        float4 tm = lmax[0][t];
        #pragma unroll
        for (int sl = 1; sl < 8; ++sl) {
            const float4 a = lsum[sl][t];
            const float4 m = lmax[sl][t];
            ts.x += a.x; ts.y += a.y; ts.z += a.z; ts.w += a.w;
            tm.x = fmaxf(tm.x, m.x); tm.y = fmaxf(tm.y, m.y);
            tm.z = fmaxf(tm.z, m.z); tm.w = fmaxf(tm.w, m.w);
        }
        const float inv = 1.0f / (float)(cnt > 0 ? cnt : 1);
        if (cnt == 0) { tm.x = 0.f; tm.y = 0.f; tm.z = 0.f; tm.w = 0.f; }
        const int c = t << 2;
        pooled[c + 0] = ts.x * inv;  pooled[c + 1] = ts.y * inv;
        pooled[c + 2] = ts.z * inv;  pooled[c + 3] = ts.w * inv;
        pooled[HIDDEN + c + 0] = tm.x; pooled[HIDDEN + c + 1] = tm.y;
        pooled[HIDDEN + c + 2] = tm.z; pooled[HIDDEN + c + 3] = tm.w;
        pooled[2 * HIDDEN + c + 0] = ts.x; pooled[2 * HIDDEN + c + 1] = ts.y;
        pooled[2 * HIDDEN + c + 2] = ts.z; pooled[2 * HIDDEN + c + 3] = ts.w;
    }
    __syncthreads();

    // ---- Phase 4: h[d] = bias[d] + sum_k pooled[k] * W[k][d] (k split in 2) ----
    const int d    = t & (HIDDEN - 1);
    const int half = t >> 7;           // 0 or 1
    const int k0   = half * 192;
    float acc = 0.f;
    const float* Wp = W + (size_t)k0 * HIDDEN + d;
    #pragma unroll 8
    for (int k = 0; k < 192; ++k) {
        acc = fmaf(pooled[k0 + k], Wp[(size_t)k * HIDDEN], acc);
    }
    hpart[half][d] = acc;
    __syncthreads();

    float h = 0.f;
    if (t < HIDDEN) h = hpart[0][t] + hpart[1][t] + bias[t];

    // ---- Phase 5: LayerNorm over the 128 h values + exact GELU ----
    float v = (t < HIDDEN) ? h : 0.f;
    #pragma unroll
    for (int off = 32; off > 0; off >>= 1) v += __shfl_xor(v, off, 64);
    if (t < HIDDEN && (t & 63) == 0) red[t >> 6] = v;
    __syncthreads();
    const float mu = (red[0] + red[1]) * (1.0f / HIDDEN);

    float dv = (t < HIDDEN) ? (h - mu) : 0.f;
    float v2 = dv * dv;
    #pragma unroll
    for (int off = 32; off > 0; off >>= 1) v2 += __shfl_xor(v2, off, 64);
    if (t < HIDDEN && (t & 63) == 0) red2[t >> 6] = v2;
    __syncthreads();
    const float var  = (red2[0] + red2[1]) * (1.0f / HIDDEN);
    const float rstd = rsqrtf(var + 1e-5f);

    if (t < HIDDEN) {
        const float xn = (h - mu) * rstd * gamma[t] + beta[t];
        const float ge = 0.5f * xn * (1.0f + erff(xn * 0.70710678118654752f));
        out[(size_t)g * HIDDEN + t] = ge;
    }
}

extern "C" void kernel_launch(void* const* d_in, const int* in_sizes, int n_in,
                              void* d_out, int out_size, void* d_ws, size_t ws_size,
                              hipStream_t stream) {
    const float* x     = (const float*)d_in[0];
    const void*  batch = d_in[1];
    // d_in[2] = num_graphs (scalar) — derived from out_size instead.
    const float* W     = (const float*)d_in[3];
    const float* bias  = (const float*)d_in[4];
    const float* gamma = (const float*)d_in[5];
    const float* beta  = (const float*)d_in[6];
    float* out = (float*)d_out;

    const int n_nodes    = in_sizes[0] / HIDDEN;
    const int num_graphs = out_size / HIDDEN;

    mp_fused<<<num_graphs, 256, 0, stream>>>(x, batch, n_nodes, W, bias,
                                             gamma, beta, out);
}

// Round 4
// 686.085 us; speedup vs baseline: 1.0018x; 1.0018x over previous
//
#include <hip/hip_runtime.h>
#include <math.h>

#define HIDDEN 128
#define LDPAD 4          // +16B per row: 4-way -> 2-way (free) LDS store aliasing

// One block (256 threads) per graph.
// Phase 1: binary-search segment bounds in sorted `batch` (L2-cached, ~20 loads).
// Phase 2: software-pipelined coalesced streaming reduce, 32 B/thread/iter,
//          16 threads per row x 16 row slots (wave = 4 contiguous rows = 2 KB).
// Phase 3: combine 16 slots -> pooled[384] = [mean | max | sum].
// Phase 4: h = pooled @ W + b (k split over 2 block-halves, W L2-resident).
// Phase 5: LayerNorm (eps=1e-5) + exact GELU, write 128 floats.
__global__ __launch_bounds__(256) void mp_fused(
    const float* __restrict__ x,
    const void* __restrict__ batch_raw,
    const int n_nodes,
    const float* __restrict__ W,
    const float* __restrict__ bias,
    const float* __restrict__ gamma,
    const float* __restrict__ beta,
    float* __restrict__ out)
{
    const int g = blockIdx.x;
    const int t = threadIdx.x;

    __shared__ int bounds[2];
    __shared__ float lds_s[16][HIDDEN + LDPAD];
    __shared__ float lds_m[16][HIDDEN + LDPAD];
    __shared__ float pooled[3 * HIDDEN];
    __shared__ float hpart[2][HIDDEN];
    __shared__ float red[2], red2[2];

    // ---- Phase 1: segment bounds via binary search (lower_bound of g, g+1) ----
    if (t < 2) {
        const int* b32 = (const int*)batch_raw;
        // int32-vs-int64 detection: batch sorted, last id ~4095 -> if int64 the
        // word at [n-1] is a high word of a small value, i.e. 0.
        const bool is64 = (b32[n_nodes - 1] == 0);
        const long long key = (long long)(g + t);
        int lo = 0, hi = n_nodes;
        while (lo < hi) {
            const int mid = (lo + hi) >> 1;
            const long long bv = is64 ? ((const long long*)batch_raw)[mid]
                                      : (long long)b32[mid];
            if (bv < key) lo = mid + 1; else hi = mid;
        }
        bounds[t] = lo;
    }
    __syncthreads();
    const int s   = bounds[0];
    const int cnt = bounds[1] - s;

    // ---- Phase 2: pipelined streaming reduce ----
    const int tcol = t & 15;    // 8-float column group (32 B)
    const int slot = t >> 4;    // row slot 0..15
    float s0=0.f,s1=0.f,s2=0.f,s3=0.f,s4=0.f,s5=0.f,s6=0.f,s7=0.f;
    float m0=-INFINITY,m1=-INFINITY,m2=-INFINITY,m3=-INFINITY,
          m4=-INFINITY,m5=-INFINITY,m6=-INFINITY,m7=-INFINITY;

    const float* xp = x + (size_t)s * HIDDEN + (tcol << 3);
    int r = slot;
    if (r < cnt) {
        float4 c0 = *(const float4*)(xp + (size_t)r * HIDDEN);
        float4 c1 = *(const float4*)(xp + (size_t)r * HIDDEN + 4);
        for (r += 16; r < cnt; r += 16) {
            const float4 n0 = *(const float4*)(xp + (size_t)r * HIDDEN);
            const float4 n1 = *(const float4*)(xp + (size_t)r * HIDDEN + 4);
            s0 += c0.x; s1 += c0.y; s2 += c0.z; s3 += c0.w;
            s4 += c1.x; s5 += c1.y; s6 += c1.z; s7 += c1.w;
            m0 = fmaxf(m0, c0.x); m1 = fmaxf(m1, c0.y);
            m2 = fmaxf(m2, c0.z); m3 = fmaxf(m3, c0.w);
            m4 = fmaxf(m4, c1.x); m5 = fmaxf(m5, c1.y);
            m6 = fmaxf(m6, c1.z); m7 = fmaxf(m7, c1.w);
            c0 = n0; c1 = n1;
        }
        s0 += c0.x; s1 += c0.y; s2 += c0.z; s3 += c0.w;
        s4 += c1.x; s5 += c1.y; s6 += c1.z; s7 += c1.w;
        m0 = fmaxf(m0, c0.x); m1 = fmaxf(m1, c0.y);
        m2 = fmaxf(m2, c0.z); m3 = fmaxf(m3, c0.w);
        m4 = fmaxf(m4, c1.x); m5 = fmaxf(m5, c1.y);
        m6 = fmaxf(m6, c1.z); m7 = fmaxf(m7, c1.w);
    }
    {
        float* ps = &lds_s[slot][tcol << 3];
        float* pm = &lds_m[slot][tcol << 3];
        *(float4*)(ps)     = make_float4(s0, s1, s2, s3);
        *(float4*)(ps + 4) = make_float4(s4, s5, s6, s7);
        *(float4*)(pm)     = make_float4(m0, m1, m2, m3);
        *(float4*)(pm + 4) = make_float4(m4, m5, m6, m7);
    }
    __syncthreads();

    // ---- Phase 3: combine 16 slots, build pooled = [mean | max | sum] ----
    if (t < HIDDEN) {
        float ssum = 0.f, smax = -INFINITY;
        #pragma unroll
        for (int sl = 0; sl < 16; ++sl) {
            ssum += lds_s[sl][t];
            smax = fmaxf(smax, lds_m[sl][t]);
        }
        const float inv = 1.0f / (float)(cnt > 0 ? cnt : 1);
        if (cnt == 0) smax = 0.f;
        pooled[t]              = ssum * inv;
        pooled[HIDDEN + t]     = smax;
        pooled[2 * HIDDEN + t] = ssum;
    }
    __syncthreads();

    // ---- Phase 4: h[d] = bias[d] + sum_k pooled[k] * W[k][d] (k split in 2) ----
    const int d    = t & (HIDDEN - 1);
    const int half = t >> 7;           // 0 or 1
    const int k0   = half * 192;
    float acc = 0.f;
    const float* Wp = W + (size_t)k0 * HIDDEN + d;
    #pragma unroll 8
    for (int k = 0; k < 192; ++k) {
        acc = fmaf(pooled[k0 + k], Wp[(size_t)k * HIDDEN], acc);
    }
    hpart[half][d] = acc;
    __syncthreads();

    float h = 0.f;
    if (t < HIDDEN) h = hpart[0][t] + hpart[1][t] + bias[t];

    // ---- Phase 5: LayerNorm over the 128 h values + exact GELU ----
    float v = (t < HIDDEN) ? h : 0.f;
    #pragma unroll
    for (int off = 32; off > 0; off >>= 1) v += __shfl_xor(v, off, 64);
    if (t < HIDDEN && (t & 63) == 0) red[t >> 6] = v;
    __syncthreads();
    const float mu = (red[0] + red[1]) * (1.0f / HIDDEN);

    float dv = (t < HIDDEN) ? (h - mu) : 0.f;
    float v2 = dv * dv;
    #pragma unroll
    for (int off = 32; off > 0; off >>= 1) v2 += __shfl_xor(v2, off, 64);
    if (t < HIDDEN && (t & 63) == 0) red2[t >> 6] = v2;
    __syncthreads();
    const float var  = (red2[0] + red2[1]) * (1.0f / HIDDEN);
    const float rstd = rsqrtf(var + 1e-5f);

    if (t < HIDDEN) {
        const float xn = (h - mu) * rstd * gamma[t] + beta[t];
        const float ge = 0.5f * xn * (1.0f + erff(xn * 0.70710678118654752f));
        out[(size_t)g * HIDDEN + t] = ge;
    }
}

extern "C" void kernel_launch(void* const* d_in, const int* in_sizes, int n_in,
                              void* d_out, int out_size, void* d_ws, size_t ws_size,
                              hipStream_t stream) {
    const float* x     = (const float*)d_in[0];
    const void*  batch = d_in[1];
    // d_in[2] = num_graphs scalar — derived from out_size instead.
    const float* W     = (const float*)d_in[3];
    const float* bias  = (const float*)d_in[4];
    const float* gamma = (const float*)d_in[5];
    const float* beta  = (const float*)d_in[6];
    float* out = (float*)d_out;

    const int n_nodes    = in_sizes[0] / HIDDEN;
    const int num_graphs = out_size / HIDDEN;

    mp_fused<<<num_graphs, 256, 0, stream>>>(x, batch, n_nodes, W, bias,
                                             gamma, beta, out);
}